// Round 1
// baseline (39.013 us; speedup 1.0000x reference)
//
#include <hip/hip_runtime.h>

typedef float f4 __attribute__((ext_vector_type(4)));

// One wave (64 lanes) per token; each wave processes TPW consecutive tokens.
// Lane i owns d-positions {4i + 256c : c=0..3} of the 1024-wide row:
//   -> global_load_dwordx4, 64 lanes x 16B = 1KB coalesced per instruction.
// All 9 weight rows (q0,q1,q2,k0,k1,k2,v0,v1,v2) held in 144 VGPRs,
// loaded once per wave, reused for TPW tokens.
#define TPW 16

__global__ __launch_bounds__(256, 2)
void moa_kernel(const float* __restrict__ tok,
                const float* __restrict__ Wq,
                const float* __restrict__ Wk,
                const float* __restrict__ Wv,
                float* __restrict__ out,
                int n_tokens) {
  const int lane = threadIdx.x & 63;
  const int wid  = (blockIdx.x << 2) | (threadIdx.x >> 6);   // blockDim == 256
  const int base = lane << 2;                                 // d offset in 256-chunk

  // ---- load 9 weight vectors into registers (coalesced, once per wave) ----
  f4 w[9][4];
  const float* Wp[3] = {Wq, Wk, Wv};
#pragma unroll
  for (int m = 0; m < 3; ++m)
#pragma unroll
    for (int e = 0; e < 3; ++e)
#pragma unroll
      for (int c = 0; c < 4; ++c)
        w[m * 3 + e][c] = *(const f4*)(Wp[m] + e * 1024 + c * 256 + base);

  const int t0 = wid * TPW;
  if (t0 >= n_tokens) return;
  const float* rowp = tok + (size_t)t0 * 1024 + base;

  // ---- software pipeline: prefetch token i+1 while computing token i ----
  f4 xc[4], xn[4];
#pragma unroll
  for (int c = 0; c < 4; ++c) xc[c] = *(const f4*)(rowp + c * 256);

  for (int i = 0; i < TPW; ++i) {
    const int t = t0 + i;
    if (t >= n_tokens) break;
    if (i < TPW - 1 && t + 1 < n_tokens) {
      const float* nrow = rowp + (size_t)(i + 1) * 1024;
#pragma unroll
      for (int c = 0; c < 4; ++c) xn[c] = *(const f4*)(nrow + c * 256);
    }

    // ---- 9 partial dot products (vector FMAs, 144 scalar FMA/lane) ----
    float acc[9];
#pragma unroll
    for (int j = 0; j < 9; ++j) {
      f4 s = xc[0] * w[j][0];
      s += xc[1] * w[j][1];
      s += xc[2] * w[j][2];
      s += xc[3] * w[j][3];
      acc[j] = (s.x + s.y) + (s.z + s.w);
    }

    // ---- butterfly reduce across the 64-lane wave (result in all lanes) ----
#pragma unroll
    for (int sh = 32; sh > 0; sh >>= 1)
#pragma unroll
      for (int j = 0; j < 9; ++j)
        acc[j] += __shfl_xor(acc[j], sh, 64);

    // ---- tiny softmax chain, computed redundantly on all lanes ----
    // q = acc[0..2], k = acc[3..5], v = acc[6..8]
    // attn row e: softmax_f(q_e * k_f); logit_e = sum_f attn*v_f
    // |q|,|k| <~ 3 so exp args are bounded; skip max-subtraction.
    float lg[3];
#pragma unroll
    for (int e = 0; e < 3; ++e) {
      float e0 = __expf(acc[e] * acc[3]);
      float e1 = __expf(acc[e] * acc[4]);
      float e2 = __expf(acc[e] * acc[5]);
      float den = (e0 + e1) + e2;
      float num = e0 * acc[6] + e1 * acc[7] + e2 * acc[8];
      lg[e] = num * __builtin_amdgcn_rcpf(den);
    }
    float w0 = __expf(lg[0]);
    float w1 = __expf(lg[1]);
    float w2 = __expf(lg[2]);
    float rs = __builtin_amdgcn_rcpf((w0 + w1) + w2);

    if (lane < 3) {
      float v = (lane == 0) ? w0 : ((lane == 1) ? w1 : w2);
      out[(size_t)t * 3 + lane] = v * rs;
    }

#pragma unroll
    for (int c = 0; c < 4; ++c) xc[c] = xn[c];
  }
}

extern "C" void kernel_launch(void* const* d_in, const int* in_sizes, int n_in,
                              void* d_out, int out_size, void* d_ws, size_t ws_size,
                              hipStream_t stream) {
  const float* tok = (const float*)d_in[0];
  const float* Wq  = (const float*)d_in[1];
  const float* Wk  = (const float*)d_in[2];
  const float* Wv  = (const float*)d_in[3];
  float* out = (float*)d_out;

  const int n_tokens = in_sizes[0] / 1024;            // B*S = 32768
  const int waves    = (n_tokens + TPW - 1) / TPW;    // 2048
  const int blocks   = (waves + 3) / 4;               // 512 (4 waves/block)

  hipLaunchKernelGGL(moa_kernel, dim3(blocks), dim3(256), 0, stream,
                     tok, Wq, Wk, Wv, out, n_tokens);
}

// Round 2
// 38.596 us; speedup vs baseline: 1.0108x; 1.0108x over previous
//
#include <hip/hip_runtime.h>

typedef float f4 __attribute__((ext_vector_type(4)));

// Tokens: [32768][1024] f32. Output: [32768][3] f32.
// Block = 256 threads, owns 128 tokens. Lane pair (2t,2t+1) owns token t,
// split over K halves h=0/1 (k in [h*512, h*512+512)).
// Stream K in 8 steps of 64; per step stage [64k x 128t] per half (32KB x2)
// into LDS, reg-staged with XOR swizzle so both the transpose write and the
// per-token read are bank-conflict-free. Weights (9x1024 f32 = 36KB) staged
// once into LDS, read as 2-address broadcast b128.
// LDS total: 32 + 32 + 36 = 100KB -> 1 block/CU.

#define NSTEPS 8

__global__ __launch_bounds__(256, 1)
void moa_kernel(const float* __restrict__ tok,
                const float* __restrict__ Wq,
                const float* __restrict__ Wk,
                const float* __restrict__ Wv,
                float* __restrict__ out) {
  __shared__ f4 ldsA[16 * 128];   // [k4][t] swizzled, half 0 chunk (32KB)
  __shared__ f4 ldsB[16 * 128];   // half 1 chunk (32KB)
  __shared__ f4 ldsW[9 * 256];    // [j][k4_global] (36KB), j = m*3+e

  const int i = threadIdx.x;
  const size_t T0 = (size_t)blockIdx.x * 128;

  // ---- stage all weights into LDS (coalesced, conflict-free) ----
  {
    const float* Wp[3] = {Wq, Wk, Wv};
#pragma unroll
    for (int m = 0; m < 3; ++m)
#pragma unroll
      for (int c = 0; c < 3; ++c)
        ldsW[(m * 3 + c) * 256 + i] = ((const f4*)Wp[m])[c * 256 + i];
  }

  // staging role: row r = p*16 + (i>>4), k4 = i&15  (per pass p, per half)
  const int srow = i >> 4;
  const int sk4  = i & 15;
  // compute role: token t = i>>1, K-half h = i&1
  const int t = i >> 1;
  const int h = i & 1;
  f4* const myChunk = h ? ldsB : ldsA;

  f4 acc[9];
#pragma unroll
  for (int j = 0; j < 9; ++j) acc[j] = (f4)0.0f;

  f4 stage[16];
  const float* tokBase = tok + T0 * 1024;

  // ---- prologue: load chunk pair for step 0 ----
#pragma unroll
  for (int p = 0; p < 8; ++p) {
#pragma unroll
    for (int c = 0; c < 2; ++c)
      stage[p * 2 + c] =
          *(const f4*)(tokBase + (size_t)(p * 16 + srow) * 1024 + c * 512 + 0 * 64 + sk4 * 4);
  }
#pragma unroll
  for (int p = 0; p < 8; ++p) {
    const int r = p * 16 + srow;
    const int w = sk4 * 128 + (r ^ (sk4 & 7));
    ldsA[w] = stage[p * 2 + 0];
    ldsB[w] = stage[p * 2 + 1];
  }
  __syncthreads();

  for (int s = 0; s < NSTEPS; ++s) {
    // ---- issue next step's global loads early (hide under compute) ----
    if (s + 1 < NSTEPS) {
#pragma unroll
      for (int p = 0; p < 8; ++p)
#pragma unroll
        for (int c = 0; c < 2; ++c)
          stage[p * 2 + c] =
              *(const f4*)(tokBase + (size_t)(p * 16 + srow) * 1024 + c * 512 + (s + 1) * 64 + sk4 * 4);
    }

    // ---- compute on chunk s ----
#pragma unroll
    for (int k4 = 0; k4 < 16; ++k4) {
      const f4 x4 = myChunk[k4 * 128 + (t ^ (k4 & 7))];
      const int wb = h * 128 + s * 16 + k4;
#pragma unroll
      for (int j = 0; j < 9; ++j) {
        const f4 w4 = ldsW[j * 256 + wb];
        acc[j] += x4 * w4;
      }
    }

    if (s + 1 < NSTEPS) {
      __syncthreads();                 // everyone done reading chunk s
#pragma unroll
      for (int p = 0; p < 8; ++p) {
        const int r = p * 16 + srow;
        const int w = sk4 * 128 + (r ^ (sk4 & 7));
        ldsA[w] = stage[p * 2 + 0];
        ldsB[w] = stage[p * 2 + 1];
      }
      __syncthreads();                 // chunk s+1 visible
    }
  }

  // ---- finish dots: horizontal add + pair reduce ----
  float s9[9];
#pragma unroll
  for (int j = 0; j < 9; ++j)
    s9[j] = (acc[j].x + acc[j].y) + (acc[j].z + acc[j].w);
#pragma unroll
  for (int j = 0; j < 9; ++j)
    s9[j] += __shfl_xor(s9[j], 1, 64);

  // ---- tiny softmax chain (both lanes redundantly) ----
  float lg[3];
#pragma unroll
  for (int e = 0; e < 3; ++e) {
    float e0 = __expf(s9[e] * s9[3]);
    float e1 = __expf(s9[e] * s9[4]);
    float e2 = __expf(s9[e] * s9[5]);
    float den = (e0 + e1) + e2;
    float num = e0 * s9[6] + e1 * s9[7] + e2 * s9[8];
    lg[e] = num * __builtin_amdgcn_rcpf(den);
  }
  float w0 = __expf(lg[0]);
  float w1 = __expf(lg[1]);
  float w2 = __expf(lg[2]);
  float rs = __builtin_amdgcn_rcpf((w0 + w1) + w2);

  const size_t T = T0 + t;
  if (h == 0) {
    out[T * 3 + 0] = w0 * rs;
    out[T * 3 + 1] = w1 * rs;
  } else {
    out[T * 3 + 2] = w2 * rs;
  }
}

extern "C" void kernel_launch(void* const* d_in, const int* in_sizes, int n_in,
                              void* d_out, int out_size, void* d_ws, size_t ws_size,
                              hipStream_t stream) {
  const float* tok = (const float*)d_in[0];
  const float* Wq  = (const float*)d_in[1];
  const float* Wk  = (const float*)d_in[2];
  const float* Wv  = (const float*)d_in[3];
  float* out = (float*)d_out;

  const int n_tokens = in_sizes[0] / 1024;      // 32768
  const int blocks   = n_tokens / 128;          // 256

  hipLaunchKernelGGL(moa_kernel, dim3(blocks), dim3(256), 0, stream,
                     tok, Wq, Wk, Wv, out);
}

// Round 3
// 30.500 us; speedup vs baseline: 1.2791x; 1.2655x over previous
//
#include <hip/hip_runtime.h>

typedef float f4 __attribute__((ext_vector_type(4)));

// One wave per 16 tokens. Lane i owns d-positions {4i + 256c : c=0..3} of the
// 1024-wide row -> global_load_dwordx4, 64 lanes x 16B = 1KB coalesced/inst.
// All 9 weight rows live in 144 VGPRs (loaded once, reused for 16 tokens).
// Cross-lane dot-product reduction via DPP adds (VALU pipe, no LDS, no
// barriers); full sum lands in lane 63; softmax computed per-lane; 3
// v_readlane broadcasts per token. 3-deep load ring keeps 12KB/wave in
// flight continuously (96KB/CU at 8 waves/CU).
#define TPW 16
#define PF  3

template <int CTRL>
__device__ __forceinline__ float dpp_add(float x) {
  int yi = __builtin_amdgcn_update_dpp(0, __float_as_int(x), CTRL, 0xF, 0xF, true);
  return x + __int_as_float(yi);
}

// After this, lane 63 holds the full 64-lane sum (other lanes hold partials).
__device__ __forceinline__ float wave_sum63(float x) {
  x = dpp_add<0x111>(x);  // row_shr:1
  x = dpp_add<0x112>(x);  // row_shr:2
  x = dpp_add<0x114>(x);  // row_shr:4
  x = dpp_add<0x118>(x);  // row_shr:8  -> lane 16r+15 = sum of row r
  x = dpp_add<0x142>(x);  // row_bcast:15
  x = dpp_add<0x143>(x);  // row_bcast:31 -> lane 63 = total
  return x;
}

__global__ __launch_bounds__(256, 2)
void moa_kernel(const float* __restrict__ tok,
                const float* __restrict__ Wq,
                const float* __restrict__ Wk,
                const float* __restrict__ Wv,
                float* __restrict__ out,
                int n_tokens) {
  const int lane = threadIdx.x & 63;
  const int wid  = (blockIdx.x << 2) | (threadIdx.x >> 6);
  const int base = lane << 2;

  // ---- 9 weight vectors -> 144 VGPRs (coalesced, once per wave) ----
  f4 w[9][4];
  const float* Wp[3] = {Wq, Wk, Wv};
#pragma unroll
  for (int m = 0; m < 3; ++m)
#pragma unroll
    for (int e = 0; e < 3; ++e)
#pragma unroll
      for (int c = 0; c < 4; ++c)
        w[m * 3 + e][c] = *(const f4*)(Wp[m] + e * 1024 + c * 256 + base);

  const int t0 = wid * TPW;
  if (t0 >= n_tokens) return;

  // ---- prologue: fill 3-deep ring ----
  f4 buf[PF][4];
#pragma unroll
  for (int i = 0; i < PF; ++i) {
    int r = t0 + i; if (r > n_tokens - 1) r = n_tokens - 1;
    const float* p = tok + (size_t)r * 1024 + base;
#pragma unroll
    for (int c = 0; c < 4; ++c) buf[i][c] = *(const f4*)(p + c * 256);
  }

  float outv = 0.0f;

#pragma unroll
  for (int i = 0; i < TPW; ++i) {
    const int s = i % PF;                 // compile-time after unroll
    // current token's data -> locals (frees the slot)
    f4 x0 = buf[s][0], x1 = buf[s][1], x2 = buf[s][2], x3 = buf[s][3];

    // prefetch token i+PF into the freed slot (issued before the compute)
    if (i + PF < TPW) {
      int r = t0 + i + PF; if (r > n_tokens - 1) r = n_tokens - 1;
      const float* p = tok + (size_t)r * 1024 + base;
#pragma unroll
      for (int c = 0; c < 4; ++c) buf[s][c] = *(const f4*)(p + c * 256);
    }

    // ---- 9 partial dots (packed FMAs) + DPP wave reduction ----
    float s9[9];
#pragma unroll
    for (int j = 0; j < 9; ++j) {
      f4 a = x0 * w[j][0];
      a += x1 * w[j][1];
      a += x2 * w[j][2];
      a += x3 * w[j][3];
      s9[j] = wave_sum63((a.x + a.y) + (a.z + a.w));
    }

    // ---- tiny softmax chain (valid in lane 63; others compute garbage) ----
    float lg[3];
#pragma unroll
    for (int e = 0; e < 3; ++e) {
      float e0 = __expf(s9[e] * s9[3]);
      float e1 = __expf(s9[e] * s9[4]);
      float e2 = __expf(s9[e] * s9[5]);
      float den = (e0 + e1) + e2;
      float num = e0 * s9[6] + e1 * s9[7] + e2 * s9[8];
      lg[e] = num * __builtin_amdgcn_rcpf(den);
    }
    float u0 = __expf(lg[0]);
    float u1 = __expf(lg[1]);
    float u2 = __expf(lg[2]);
    float rs = __builtin_amdgcn_rcpf((u0 + u1) + u2);

    // broadcast lane 63's final three weights to all lanes
    float r0 = __int_as_float(__builtin_amdgcn_readlane(__float_as_int(u0 * rs), 63));
    float r1 = __int_as_float(__builtin_amdgcn_readlane(__float_as_int(u1 * rs), 63));
    float r2 = __int_as_float(__builtin_amdgcn_readlane(__float_as_int(u2 * rs), 63));

    // collect into the per-lane output slot (token i -> lanes 3i..3i+2)
    const int rel = lane - 3 * i;
    outv = (rel == 0) ? r0 : outv;
    outv = (rel == 1) ? r1 : outv;
    outv = (rel == 2) ? r2 : outv;
  }

  // ---- one coalesced 192B store per wave ----
  const int oidx = t0 * 3 + lane;
  if (lane < 3 * TPW && oidx < n_tokens * 3) out[oidx] = outv;
}

extern "C" void kernel_launch(void* const* d_in, const int* in_sizes, int n_in,
                              void* d_out, int out_size, void* d_ws, size_t ws_size,
                              hipStream_t stream) {
  const float* tok = (const float*)d_in[0];
  const float* Wq  = (const float*)d_in[1];
  const float* Wk  = (const float*)d_in[2];
  const float* Wv  = (const float*)d_in[3];
  float* out = (float*)d_out;

  const int n_tokens = in_sizes[0] / 1024;           // 32768
  const int waves    = (n_tokens + TPW - 1) / TPW;   // 2048
  const int blocks   = (waves + 3) / 4;              // 512

  hipLaunchKernelGGL(moa_kernel, dim3(blocks), dim3(256), 0, stream,
                     tok, Wq, Wk, Wv, out, n_tokens);
}